// Round 19
// baseline (24.762 us; speedup 1.0000x reference)
//
#include <hip/hip_runtime.h>
#include <hip/hip_bf16.h>

// Problem: B=8, CIN=8, COUT=8, NX=NT=512, M1=M2=4.
// out[b,o,z,i] = Re( sum_{m,kw} c2[b,o,m,kw] e^{2pi i (m z + kw i)/512} ) / 65536
// R19: R18 pipeline + two fixes: (1) s_sleep(2)->s_sleep(32) (spin traffic /16);
// (2) producers take eval tasks for b6,b7 after reading (write phase at full
// 2048-block occupancy; consumers single-task).
//   blocks 0..511: dft task blk (b0..3), dft task blk+512 (b4..7),
//                  then eval task 1536+blk (b6,7).
//   blocks 512..2047: eval task blk-512 (b0..5).
// Ledger: R17=R18=24.4; T_read~10us T_write~13us (R16); NT stores +4us (R11);
// grid.sync ~100us (R5). Fallback: proven R17 pair.

#define PI2 6.283185307179586f

typedef float vfloat4 __attribute__((ext_vector_type(4)));

__device__ __forceinline__ void fsincos(float r, float* s, float* c) {
    r = r - floorf(r);
    *s = __builtin_amdgcn_sinf(r);
    *c = __builtin_amdgcn_cosf(r);
}

__device__ __forceinline__ float foldred(float u, float v, int msk, int lane) {
    float send = (lane & msk) ? u : v;
    float recv = __shfl_xor(send, msk, 64);
    return ((lane & msk) ? v : u) + recv;
}

__device__ __forceinline__ float fold8(const float* ar, const float* ai, int lane) {
    float A0 = foldred(ar[0], ai[0], 1, lane);
    float A1 = foldred(ar[1], ai[1], 1, lane);
    float A2 = foldred(ar[2], ai[2], 1, lane);
    float A3 = foldred(ar[3], ai[3], 1, lane);
    float B0 = foldred(A0, A1, 2, lane);
    float B1 = foldred(A2, A3, 2, lane);
    float C  = foldred(B0, B1, 4, lane);
    C += __shfl_xor(C, 8, 64);
    C += __shfl_xor(C, 16, 64);
    C += __shfl_xor(C, 32, 64);
    return C;
}

// ---- producer task: dft for (bc,g), 4 waves x 4 rows, Yg atomic stores ----
__device__ __forceinline__ void dft_task(const float* __restrict__ x,
                                         float* __restrict__ Yg,
                                         float vals[4][64],
                                         int task, int lane, int w) {
    int bc = task >> 4;           // b*8+ci
    int g  = task & 15;
    int y0 = g * 16 + w * 4;

    const float* base = x + (size_t)bc * 512 * 512;
    vfloat4 A0[4], A1[4];
#pragma unroll
    for (int r = 0; r < 4; ++r) {
        const vfloat4* row = (const vfloat4*)(base + (size_t)(2 * (y0 + r)) * 512);
        A0[r] = __builtin_nontemporal_load(&row[lane]);
        A1[r] = __builtin_nontemporal_load(&row[lane + 64]);
    }

    float s, c;
    fsincos((float)lane * 0.0078125f, &s, &c);      // lane/128
    float er[4], ei[4], orE[4], oiE[4];
    er[0] = 1.f; ei[0] = 0.f;
    er[1] = c;   ei[1] = -s;
    er[2] = er[1]*er[1] - ei[1]*ei[1];  ei[2] = 2.f*er[1]*ei[1];
    er[3] = er[2]*er[1] - ei[2]*ei[1];  ei[3] = er[2]*ei[1] + ei[2]*er[1];
    const float rr1 = 0.999698818696204f, ri1 = -0.024541228522912f;
    const float rr2 = 0.998795456205172f, ri2 = -0.049067674327418f;
    const float rr3 = 0.997290456678690f, ri3 = -0.073564563599667f;
    orE[0] = 1.f; oiE[0] = 0.f;
    orE[1] = er[1]*rr1 - ei[1]*ri1;  oiE[1] = er[1]*ri1 + ei[1]*rr1;
    orE[2] = er[2]*rr2 - ei[2]*ri2;  oiE[2] = er[2]*ri2 + ei[2]*rr2;
    orE[3] = er[3]*rr3 - ei[3]*ri3;  oiE[3] = er[3]*ri3 + ei[3]*rr3;

    int midx = lane >> 3;
    float mf = (midx < 4) ? (float)midx : (float)(midx - 8);
    float snm, csm;
    fsincos(mf * (float)y0 * 0.00390625f, &snm, &csm);
    float cs = csm, ty = -snm;
    float smm, cmm;
    fsincos(mf * 0.00390625f, &smm, &cmm);

    float acc = 0.f;
#pragma unroll
    for (int r = 0; r < 4; ++r) {
        float s0 = A0[r][0] + A1[r][0], d0 = A0[r][0] - A1[r][0];
        float s2 = A0[r][2] + A1[r][2], d2 = A0[r][2] - A1[r][2];
        float ar[4], ai[4];
#pragma unroll
        for (int kw = 0; kw < 4; ++kw) {
            float E = (kw & 1) ? d0 : s0;
            float O = (kw & 1) ? d2 : s2;
            ar[kw] = E * er[kw] + O * orE[kw];
            ai[kw] = E * ei[kw] + O * oiE[kw];
        }
        float C  = fold8(ar, ai, lane);
        float pt = __shfl_xor(C, 1, 64);
        float sel = (lane & 1) ? ty : -ty;
        acc += C * cs + pt * sel;
        float nc = cs * cmm + ty * smm;
        float nt = ty * cmm - cs * smm;
        cs = nc; ty = nt;
    }
    vals[w][lane] = acc;
    __syncthreads();

    if (w == 0) {
        int b = bc >> 3, ci = bc & 7;
        float sum = vals[0][lane] + vals[1][lane] + vals[2][lane] + vals[3][lane];
        __hip_atomic_store(&Yg[((size_t)((b * 16 + g) * 8 + ci)) * 64 + lane], sum,
                           __ATOMIC_RELEASE, __HIP_MEMORY_SCOPE_AGENT);
    }
    __syncthreads();   // drains vmcnt -> stores visible before signal
}

// ---- consumer task: spin for batch, mix c2 from Yg, eval 8 z-rows ----
__device__ __forceinline__ void consume_task(const float* __restrict__ w1,
                                             const float* __restrict__ w2,
                                             float* __restrict__ Yg,
                                             unsigned int* __restrict__ done,
                                             float* __restrict__ out,
                                             float vals[4][64], float lcf[64],
                                             int e, int lane, int w) {
    int bo = e >> 5, chunk = e & 31;
    int b = bo >> 3, o = bo & 7;

    if (threadIdx.x == 0) {
        while (__hip_atomic_load(&done[b], __ATOMIC_ACQUIRE,
                                 __HIP_MEMORY_SCOPE_AGENT) < 128u)
            __builtin_amdgcn_s_sleep(32);      // ~0.85us poll period
    }
    __syncthreads();

    // ---- mix ----
    {
        int midx = lane >> 3, kw = (lane >> 1) & 3, ri = lane & 1, mx = midx & 3;
        const float* wt = (midx < 4) ? w1 : w2;
        float wr_[8], swi_[8];
#pragma unroll
        for (int ci = 0; ci < 8; ++ci) {
            const float* wp = wt + ((((ci * 8 + o) * 4 + mx) * 4 + kw) * 2);
            wr_[ci]  = wp[0];
            swi_[ci] = ri ? wp[1] : -wp[1];
        }
        float acc = 0.f;
#pragma unroll
        for (int gi = 0; gi < 4; ++gi) {
            int g = w + gi * 4;
            float* Yp = Yg + ((size_t)((b * 16 + g) * 8)) * 64 + lane;
#pragma unroll
            for (int ci = 0; ci < 8; ++ci) {
                float Yv = __hip_atomic_load(Yp + ci * 64, __ATOMIC_RELAXED,
                                             __HIP_MEMORY_SCOPE_AGENT);
                float pt = __shfl_xor(Yv, 1, 64);
                acc += Yv * wr_[ci] + pt * swi_[ci];
            }
        }
        vals[w][lane] = acc;
    }
    __syncthreads();
    if (w == 0)
        lcf[lane] = vals[0][lane] + vals[1][lane] + vals[2][lane] + vals[3][lane];
    __syncthreads();

    // ---- eval ----
    float c1b, s1b;
    fsincos((float)lane * 0.0078125f, &s1b, &c1b);
    const float cr = 0.99992470183839f;
    const float sr = 0.012271538285720f;
    const float inv = 1.0f / 65536.0f;

    int ll = lane & 31;
    int kw = ll & 3, midx = (ll >> 2) & 7;
    float m = (midx < 4) ? (float)midx : (float)(midx - 8);
    float2 cc = make_float2(lcf[(midx * 4 + kw) * 2], lcf[(midx * 4 + kw) * 2 + 1]);
    float sgm = (midx & 1) ? -1.f : 1.f;

#pragma unroll
    for (int ez = 0; ez < 2; ++ez) {
        int z = chunk * 8 + w * 2 + ez;

        float s, c;
        fsincos(m * (float)z * 0.001953125f, &s, &c);
        float hx = cc.x * c - cc.y * s;
        float hy = cc.x * s + cc.y * c;
        float gx = sgm * hx, gy = sgm * hy;

        float F = foldred(hx, hy, 4, lane);
        F += __shfl_xor(F, 8, 64);
        F += __shfl_xor(F, 16, 64);
        float G = foldred(gx, gy, 4, lane);
        G += __shfl_xor(G, 8, 64);
        G += __shfl_xor(G, 16, 64);
        float h0x = __shfl(F, 0, 64);
        float h1x = __shfl(F, 1, 64), h2x = __shfl(F, 2, 64), h3x = __shfl(F, 3, 64);
        float h1y = __shfl(F, 5, 64), h2y = __shfl(F, 6, 64), h3y = __shfl(F, 7, 64);
        float g0x = __shfl(G, 0, 64);
        float g1x = __shfl(G, 1, 64), g2x = __shfl(G, 2, 64), g3x = __shfl(G, 3, 64);
        float g1y = __shfl(G, 5, 64), g2y = __shfl(G, 6, 64), g3y = __shfl(G, 7, 64);

        float* orow0 = out + (size_t)(bo * 512 + z) * 512;
        float* orow1 = orow0 + 256 * 512;

        float c1 = c1b, s1 = s1b;
        vfloat4 r0, r1, q0, q1;
#pragma unroll
        for (int j = 0; j < 4; ++j) {
            float c2a = c1 * c1 - s1 * s1, s2a = 2.f * c1 * s1;
            float c3a = c2a * c1 - s2a * s1, s3a = s2a * c1 + c2a * s1;
            float t1 = h1x * c1  - h1y * s1;
            float t2 = h2x * c2a - h2y * s2a;
            float t3 = h3x * c3a - h3y * s3a;
            r0[j] = (h0x + t1 + t2 + t3) * inv;
            r1[j] = (h0x - t1 + t2 - t3) * inv;
            float u1 = g1x * c1  - g1y * s1;
            float u2 = g2x * c2a - g2y * s2a;
            float u3 = g3x * c3a - g3y * s3a;
            q0[j] = (g0x + u1 + u2 + u3) * inv;
            q1[j] = (g0x - u1 + u2 - u3) * inv;
            float nc = c1 * cr - s1 * sr;
            float ns = s1 * cr + c1 * sr;
            c1 = nc; s1 = ns;
        }
        __builtin_nontemporal_store(r0, (vfloat4*)(orow0 + lane * 4));
        __builtin_nontemporal_store(r1, (vfloat4*)(orow0 + 256 + lane * 4));
        __builtin_nontemporal_store(q0, (vfloat4*)(orow1 + lane * 4));
        __builtin_nontemporal_store(q1, (vfloat4*)(orow1 + 256 + lane * 4));
    }
}

// ---------------- pipelined kernel ----------------
__global__ __launch_bounds__(256, 8) void k_pipe(const float* __restrict__ x,
                                                 const float* __restrict__ w1,
                                                 const float* __restrict__ w2,
                                                 float* __restrict__ Yg,
                                                 unsigned int* __restrict__ done,
                                                 float* __restrict__ out) {
    __shared__ float vals[4][64];
    __shared__ float lcf[64];

    int lane = threadIdx.x & 63;
    int w    = threadIdx.x >> 6;
    int blk  = blockIdx.x;

    if (blk < 512) {
        // producer: 2 dft tasks (b0..3 then b4..7), then eval task for b6/b7
#pragma unroll
        for (int rnd = 0; rnd < 2; ++rnd) {
            int task = blk + rnd * 512;
            dft_task(x, Yg, vals, task, lane, w);
            if (threadIdx.x == 0) {
                int b = task >> 7;
                __hip_atomic_fetch_add(&done[b], 1u, __ATOMIC_RELEASE,
                                       __HIP_MEMORY_SCOPE_AGENT);
            }
        }
        consume_task(w1, w2, Yg, done, out, vals, lcf, 1536 + blk, lane, w);
    } else {
        consume_task(w1, w2, Yg, done, out, vals, lcf, blk - 512, lane, w);
    }
}

// ---------------- fallback: proven R17 two-kernel path ----------------
__global__ __launch_bounds__(256) void k_dft_t(const float* __restrict__ x,
                                               float* __restrict__ Yg) {
    __shared__ float vals[4][64];
    int lane = threadIdx.x & 63;
    int w    = threadIdx.x >> 6;
    int task = blockIdx.x;
    int bc = task >> 4, g = task & 15;
    int y0 = g * 16 + w * 4;

    const float* base = x + (size_t)bc * 512 * 512;
    vfloat4 A0[4], A1[4];
#pragma unroll
    for (int r = 0; r < 4; ++r) {
        const vfloat4* row = (const vfloat4*)(base + (size_t)(2 * (y0 + r)) * 512);
        A0[r] = __builtin_nontemporal_load(&row[lane]);
        A1[r] = __builtin_nontemporal_load(&row[lane + 64]);
    }
    float s, c;
    fsincos((float)lane * 0.0078125f, &s, &c);
    float er[4], ei[4], orE[4], oiE[4];
    er[0] = 1.f; ei[0] = 0.f;
    er[1] = c;   ei[1] = -s;
    er[2] = er[1]*er[1] - ei[1]*ei[1];  ei[2] = 2.f*er[1]*ei[1];
    er[3] = er[2]*er[1] - ei[2]*ei[1];  ei[3] = er[2]*ei[1] + ei[2]*er[1];
    const float rr1 = 0.999698818696204f, ri1 = -0.024541228522912f;
    const float rr2 = 0.998795456205172f, ri2 = -0.049067674327418f;
    const float rr3 = 0.997290456678690f, ri3 = -0.073564563599667f;
    orE[0] = 1.f; oiE[0] = 0.f;
    orE[1] = er[1]*rr1 - ei[1]*ri1;  oiE[1] = er[1]*ri1 + ei[1]*rr1;
    orE[2] = er[2]*rr2 - ei[2]*ri2;  oiE[2] = er[2]*ri2 + ei[2]*rr2;
    orE[3] = er[3]*rr3 - ei[3]*ri3;  oiE[3] = er[3]*ri3 + ei[3]*rr3;

    int midx = lane >> 3;
    float mf = (midx < 4) ? (float)midx : (float)(midx - 8);
    float snm, csm;
    fsincos(mf * (float)y0 * 0.00390625f, &snm, &csm);
    float cs = csm, ty = -snm;
    float smm, cmm;
    fsincos(mf * 0.00390625f, &smm, &cmm);

    float acc = 0.f;
#pragma unroll
    for (int r = 0; r < 4; ++r) {
        float s0 = A0[r][0] + A1[r][0], d0 = A0[r][0] - A1[r][0];
        float s2 = A0[r][2] + A1[r][2], d2 = A0[r][2] - A1[r][2];
        float ar[4], ai[4];
#pragma unroll
        for (int kw = 0; kw < 4; ++kw) {
            float E = (kw & 1) ? d0 : s0;
            float O = (kw & 1) ? d2 : s2;
            ar[kw] = E * er[kw] + O * orE[kw];
            ai[kw] = E * ei[kw] + O * oiE[kw];
        }
        float C  = fold8(ar, ai, lane);
        float pt = __shfl_xor(C, 1, 64);
        float sel = (lane & 1) ? ty : -ty;
        acc += C * cs + pt * sel;
        float nc = cs * cmm + ty * smm;
        float nt = ty * cmm - cs * smm;
        cs = nc; ty = nt;
    }
    vals[w][lane] = acc;
    __syncthreads();
    if (threadIdx.x < 64) {
        int b = bc >> 3, ci = bc & 7;
        float sum = vals[0][lane] + vals[1][lane] + vals[2][lane] + vals[3][lane];
        Yg[((size_t)((b * 16 + g) * 8 + ci)) * 64 + lane] = sum;
    }
}

__global__ __launch_bounds__(256) void k_mix_eval(const float* __restrict__ Yg,
                                                  const float* __restrict__ w1,
                                                  const float* __restrict__ w2,
                                                  float* __restrict__ out) {
    __shared__ float vals[4][64];
    __shared__ float lcf[64];
    int lane  = threadIdx.x & 63;
    int w     = threadIdx.x >> 6;
    int bo    = blockIdx.x >> 5;
    int chunk = blockIdx.x & 31;
    int b = bo >> 3, o = bo & 7;
    {
        int midx = lane >> 3, kw = (lane >> 1) & 3, ri = lane & 1, mx = midx & 3;
        const float* wt = (midx < 4) ? w1 : w2;
        float wr_[8], swi_[8];
#pragma unroll
        for (int ci = 0; ci < 8; ++ci) {
            const float* wp = wt + ((((ci * 8 + o) * 4 + mx) * 4 + kw) * 2);
            wr_[ci]  = wp[0];
            swi_[ci] = ri ? wp[1] : -wp[1];
        }
        float acc = 0.f;
#pragma unroll
        for (int gi = 0; gi < 4; ++gi) {
            int g = w + gi * 4;
            const float* Yp = Yg + ((size_t)((b * 16 + g) * 8)) * 64 + lane;
#pragma unroll
            for (int ci = 0; ci < 8; ++ci) {
                float Yv = Yp[ci * 64];
                float pt = __shfl_xor(Yv, 1, 64);
                acc += Yv * wr_[ci] + pt * swi_[ci];
            }
        }
        vals[w][lane] = acc;
    }
    __syncthreads();
    if (w == 0)
        lcf[lane] = vals[0][lane] + vals[1][lane] + vals[2][lane] + vals[3][lane];
    __syncthreads();

    float c1b, s1b;
    fsincos((float)lane * 0.0078125f, &s1b, &c1b);
    const float cr = 0.99992470183839f;
    const float sr = 0.012271538285720f;
    const float inv = 1.0f / 65536.0f;
    int ll = lane & 31;
    int kw = ll & 3, midx = (ll >> 2) & 7;
    float m = (midx < 4) ? (float)midx : (float)(midx - 8);
    float2 cc = make_float2(lcf[ll * 2], lcf[ll * 2 + 1]);
    float sgm = (midx & 1) ? -1.f : 1.f;
#pragma unroll
    for (int e = 0; e < 2; ++e) {
        int z = chunk * 8 + w * 2 + e;
        float s, c;
        fsincos(m * (float)z * 0.001953125f, &s, &c);
        float hx = cc.x * c - cc.y * s;
        float hy = cc.x * s + cc.y * c;
        float gx = sgm * hx, gy = sgm * hy;
        float F = foldred(hx, hy, 4, lane);
        F += __shfl_xor(F, 8, 64);
        F += __shfl_xor(F, 16, 64);
        float G = foldred(gx, gy, 4, lane);
        G += __shfl_xor(G, 8, 64);
        G += __shfl_xor(G, 16, 64);
        float h0x = __shfl(F, 0, 64);
        float h1x = __shfl(F, 1, 64), h2x = __shfl(F, 2, 64), h3x = __shfl(F, 3, 64);
        float h1y = __shfl(F, 5, 64), h2y = __shfl(F, 6, 64), h3y = __shfl(F, 7, 64);
        float g0x = __shfl(G, 0, 64);
        float g1x = __shfl(G, 1, 64), g2x = __shfl(G, 2, 64), g3x = __shfl(G, 3, 64);
        float g1y = __shfl(G, 5, 64), g2y = __shfl(G, 6, 64), g3y = __shfl(G, 7, 64);
        float* orow0 = out + (size_t)(bo * 512 + z) * 512;
        float* orow1 = orow0 + 256 * 512;
        float c1 = c1b, s1 = s1b;
        vfloat4 r0, r1, q0, q1;
#pragma unroll
        for (int j = 0; j < 4; ++j) {
            float c2a = c1 * c1 - s1 * s1, s2a = 2.f * c1 * s1;
            float c3a = c2a * c1 - s2a * s1, s3a = s2a * c1 + c2a * s1;
            float t1 = h1x * c1  - h1y * s1;
            float t2 = h2x * c2a - h2y * s2a;
            float t3 = h3x * c3a - h3y * s3a;
            r0[j] = (h0x + t1 + t2 + t3) * inv;
            r1[j] = (h0x - t1 + t2 - t3) * inv;
            float u1 = g1x * c1  - g1y * s1;
            float u2 = g2x * c2a - g2y * s2a;
            float u3 = g3x * c3a - g3y * s3a;
            q0[j] = (g0x + u1 + u2 + u3) * inv;
            q1[j] = (g0x - u1 + u2 - u3) * inv;
            float nc = c1 * cr - s1 * sr;
            float ns = s1 * cr + c1 * sr;
            c1 = nc; s1 = ns;
        }
        __builtin_nontemporal_store(r0, (vfloat4*)(orow0 + lane * 4));
        __builtin_nontemporal_store(r1, (vfloat4*)(orow0 + 256 + lane * 4));
        __builtin_nontemporal_store(q0, (vfloat4*)(orow1 + lane * 4));
        __builtin_nontemporal_store(q1, (vfloat4*)(orow1 + 256 + lane * 4));
    }
}

extern "C" void kernel_launch(void* const* d_in, const int* in_sizes, int n_in,
                              void* d_out, int out_size, void* d_ws, size_t ws_size,
                              hipStream_t stream) {
    const float* x  = (const float*)d_in[0];
    const float* w1 = (const float*)d_in[3];
    const float* w2 = (const float*)d_in[4];
    float* out = (float*)d_out;

    float* Yg = (float*)d_ws;                        // [8][16][8][64] = 256 KB
    unsigned int* done = (unsigned int*)(Yg + 65536);// 8 uints

    int maxb = 0;
    bool pipe_ok =
        (hipOccupancyMaxActiveBlocksPerMultiprocessor(&maxb, (const void*)k_pipe, 256, 0)
             == hipSuccess) && (maxb >= 8);

    if (pipe_ok) {
        hipMemsetAsync(done, 0, 8 * sizeof(unsigned int), stream);
        k_pipe<<<2048, 256, 0, stream>>>(x, w1, w2, Yg, done, out);
    } else {
        k_dft_t<<<1024, 256, 0, stream>>>(x, Yg);
        k_mix_eval<<<2048, 256, 0, stream>>>(Yg, w1, w2, out);
    }
}

// Round 20
// 24.281 us; speedup vs baseline: 1.0198x; 1.0198x over previous
//
#include <hip/hip_runtime.h>
#include <hip/hip_bf16.h>

// Problem: B=8, CIN=8, COUT=8, NX=NT=512, M1=M2=4.
// out[b,o,z,i] = Re( sum_{m,kw} c2[b,o,m,kw] e^{2pi i (m z + kw i)/512} ) / 65536
// FINAL (R17 verbatim, proven 24.44us): two kernels.
//   K_A: t-DFT + y-twiddle, 4 rows/wave, 16-row block sum -> Yg (256 KB).
//   K_B: per-(bo,chunk) block: mix c2 from Yg -> LDS, eval 8 z-rows, NT stores.
// Structural floor: read 32MB @ ~3.0 TB/s (bit-11-fixed addresses, half-channel)
// ~10.5us + write 64MB @ ~5.5 TB/s NT ~13us + boundary ~1us = 24.5 ~= measured.
// Overlap refused in 4 distinct structures (R14/R15/R18/R19). Ledger: NT stores
// +4us (R11); HW sincos +1.2us (R17); grid.sync ~100us (R5); splits -2us (R12).

#define PI2 6.283185307179586f

typedef float vfloat4 __attribute__((ext_vector_type(4)));

// sin/cos of 2*pi*r via HW trans ops (v_sin_f32 input is revolutions).
__device__ __forceinline__ void fsincos(float r, float* s, float* c) {
    r = r - floorf(r);
    *s = __builtin_amdgcn_sinf(r);
    *c = __builtin_amdgcn_cosf(r);
}

// fold-reduce: lanes with (lane&msk)==0 end holding u+partner_u; lanes with
// (lane&msk)!=0 end holding v+partner_v.
__device__ __forceinline__ float foldred(float u, float v, int msk, int lane) {
    float send = (lane & msk) ? u : v;
    float recv = __shfl_xor(send, msk, 64);
    return ((lane & msk) ? v : u) + recv;
}

// full fold of 4 complex accumulators -> every lane holds (kw=(l>>1)&3, ri=l&1)
__device__ __forceinline__ float fold8(const float* ar, const float* ai, int lane) {
    float A0 = foldred(ar[0], ai[0], 1, lane);
    float A1 = foldred(ar[1], ai[1], 1, lane);
    float A2 = foldred(ar[2], ai[2], 1, lane);
    float A3 = foldred(ar[3], ai[3], 1, lane);
    float B0 = foldred(A0, A1, 2, lane);
    float B1 = foldred(A2, A3, 2, lane);
    float C  = foldred(B0, B1, 4, lane);
    C += __shfl_xor(C, 8, 64);
    C += __shfl_xor(C, 16, 64);
    C += __shfl_xor(C, 32, 64);
    return C;
}

// ---- K_A: t-DFT + y-twiddle, 4 rows per wave, 16-row block sum. 1024x256. ----
__global__ __launch_bounds__(256) void k_dft_t(const float* __restrict__ x,
                                               float* __restrict__ Yg) {
    __shared__ float vals[4][64];
    int lane = threadIdx.x & 63;
    int w    = threadIdx.x >> 6;         // 0..3
    int bc   = blockIdx.x >> 4;          // b*8+ci
    int g    = blockIdx.x & 15;
    int y0   = g * 16 + w * 4;           // this wave: xs-rows y0..y0+3

    const float* base = x + (size_t)bc * 512 * 512;

    vfloat4 A0[4], A1[4];
#pragma unroll
    for (int r = 0; r < 4; ++r) {
        const vfloat4* row = (const vfloat4*)(base + (size_t)(2 * (y0 + r)) * 512);
        A0[r] = __builtin_nontemporal_load(&row[lane]);
        A1[r] = __builtin_nontemporal_load(&row[lane + 64]);
    }

    // twE = e^{-2pi i (2L)/256} = e^{-2pi i L/128}
    float s, c;
    fsincos((float)lane * 0.0078125f, &s, &c);      // lane/128, exact
    float er[4], ei[4], orE[4], oiE[4];
    er[0] = 1.f; ei[0] = 0.f;
    er[1] = c;   ei[1] = -s;
    er[2] = er[1]*er[1] - ei[1]*ei[1];  ei[2] = 2.f*er[1]*ei[1];
    er[3] = er[2]*er[1] - ei[2]*ei[1];  ei[3] = er[2]*ei[1] + ei[2]*er[1];
    const float rr1 = 0.999698818696204f, ri1 = -0.024541228522912f; // e^{-2pi i/256}
    const float rr2 = 0.998795456205172f, ri2 = -0.049067674327418f; // ^2
    const float rr3 = 0.997290456678690f, ri3 = -0.073564563599667f; // ^3
    orE[0] = 1.f; oiE[0] = 0.f;
    orE[1] = er[1]*rr1 - ei[1]*ri1;  oiE[1] = er[1]*ri1 + ei[1]*rr1;
    orE[2] = er[2]*rr2 - ei[2]*ri2;  oiE[2] = er[2]*ri2 + ei[2]*rr2;
    orE[3] = er[3]*rr3 - ei[3]*ri3;  oiE[3] = er[3]*ri3 + ei[3]*rr3;

    int midx = lane >> 3;
    float mf = (midx < 4) ? (float)midx : (float)(midx - 8);
    float snm, csm;
    fsincos(mf * (float)y0 * 0.00390625f, &snm, &csm);   // m*y0/256, exact
    float cs = csm, ty = -snm;
    float smm, cmm;
    fsincos(mf * 0.00390625f, &smm, &cmm);               // m/256, rotation per +1 row

    float acc = 0.f;
#pragma unroll
    for (int r = 0; r < 4; ++r) {
        float s0 = A0[r][0] + A1[r][0], d0 = A0[r][0] - A1[r][0];
        float s2 = A0[r][2] + A1[r][2], d2 = A0[r][2] - A1[r][2];
        float ar[4], ai[4];
#pragma unroll
        for (int kw = 0; kw < 4; ++kw) {
            float E = (kw & 1) ? d0 : s0;      // tw(t+128)^kw = (-1)^kw tw(t)^kw
            float O = (kw & 1) ? d2 : s2;
            ar[kw] = E * er[kw] + O * orE[kw];
            ai[kw] = E * ei[kw] + O * oiE[kw];
        }
        float C  = fold8(ar, ai, lane);
        float pt = __shfl_xor(C, 1, 64);
        float sel = (lane & 1) ? ty : -ty;
        acc += C * cs + pt * sel;
        float nc = cs * cmm + ty * smm;
        float nt = ty * cmm - cs * smm;
        cs = nc; ty = nt;
    }
    vals[w][lane] = acc;
    __syncthreads();

    if (threadIdx.x < 64) {
        int b = bc >> 3, ci = bc & 7;
        float sum = vals[0][lane] + vals[1][lane] + vals[2][lane] + vals[3][lane];
        Yg[((size_t)((b * 16 + g) * 8 + ci)) * 64 + lane] = sum;
    }
}

// ---- K_B: block = (bo, chunk<32). Phase 1: c2 from Yg. Phase 2: eval 8 z. ----
__global__ __launch_bounds__(256) void k_mix_eval(const float* __restrict__ Yg,
                                                  const float* __restrict__ w1,
                                                  const float* __restrict__ w2,
                                                  float* __restrict__ out) {
    __shared__ float vals[4][64];
    __shared__ float lcf[64];     // c2[midx*8+kw*2+ri], indexed by lane role

    int lane  = threadIdx.x & 63;
    int w     = threadIdx.x >> 6;           // wave 0..3
    int bo    = blockIdx.x >> 5;            // b*8+o
    int chunk = blockIdx.x & 31;
    int b = bo >> 3, o = bo & 7;

    // ---- Phase 1: lane role (midx,kw,ri); sum over g (strided by wave) and ci
    {
        int midx = lane >> 3, kw = (lane >> 1) & 3, ri = lane & 1, mx = midx & 3;
        const float* wt = (midx < 4) ? w1 : w2;
        float wr_[8], swi_[8];
#pragma unroll
        for (int ci = 0; ci < 8; ++ci) {
            const float* wp = wt + ((((ci * 8 + o) * 4 + mx) * 4 + kw) * 2);
            wr_[ci]  = wp[0];
            swi_[ci] = ri ? wp[1] : -wp[1];
        }
        float acc = 0.f;
#pragma unroll
        for (int gi = 0; gi < 4; ++gi) {
            int g = w + gi * 4;
            const float* Yp = Yg + ((size_t)((b * 16 + g) * 8)) * 64 + lane;
#pragma unroll
            for (int ci = 0; ci < 8; ++ci) {
                float Yv = Yp[ci * 64];
                float pt = __shfl_xor(Yv, 1, 64);
                acc += Yv * wr_[ci] + pt * swi_[ci];
            }
        }
        vals[w][lane] = acc;
    }
    __syncthreads();
    if (w == 0)
        lcf[lane] = vals[0][lane] + vals[1][lane] + vals[2][lane] + vals[3][lane];
    __syncthreads();

    // ---- Phase 2: eval. 2 z-tasks per wave; task covers rows z and z+256. ----
    float c1b, s1b;
    fsincos((float)lane * 0.0078125f, &s1b, &c1b);   // lane*4/512 = lane/128, exact
    const float cr = 0.99992470183839f;     // cos(2pi/512)
    const float sr = 0.012271538285720f;    // sin(2pi/512)
    const float inv = 1.0f / 65536.0f;

    int ll = lane & 31;
    int kw = ll & 3, midx = (ll >> 2) & 7;
    float m = (midx < 4) ? (float)midx : (float)(midx - 8);
    float2 cc = make_float2(lcf[ll * 2], lcf[ll * 2 + 1]);
    float sgm = (midx & 1) ? -1.f : 1.f;

#pragma unroll
    for (int e = 0; e < 2; ++e) {
        int z = chunk * 8 + w * 2 + e;      // [0,256)

        float s, c;
        fsincos(m * (float)z * 0.001953125f, &s, &c);   // m*z/512, exact
        float hx = cc.x * c - cc.y * s;
        float hy = cc.x * s + cc.y * c;
        float gx = sgm * hx, gy = sgm * hy;

        float F = foldred(hx, hy, 4, lane);
        F += __shfl_xor(F, 8, 64);
        F += __shfl_xor(F, 16, 64);
        float G = foldred(gx, gy, 4, lane);
        G += __shfl_xor(G, 8, 64);
        G += __shfl_xor(G, 16, 64);
        float h0x = __shfl(F, 0, 64);
        float h1x = __shfl(F, 1, 64), h2x = __shfl(F, 2, 64), h3x = __shfl(F, 3, 64);
        float h1y = __shfl(F, 5, 64), h2y = __shfl(F, 6, 64), h3y = __shfl(F, 7, 64);
        float g0x = __shfl(G, 0, 64);
        float g1x = __shfl(G, 1, 64), g2x = __shfl(G, 2, 64), g3x = __shfl(G, 3, 64);
        float g1y = __shfl(G, 5, 64), g2y = __shfl(G, 6, 64), g3y = __shfl(G, 7, 64);

        float* orow0 = out + (size_t)(bo * 512 + z) * 512;
        float* orow1 = orow0 + 256 * 512;

        float c1 = c1b, s1 = s1b;
        vfloat4 r0, r1, q0, q1;
#pragma unroll
        for (int j = 0; j < 4; ++j) {
            float c2a = c1 * c1 - s1 * s1, s2a = 2.f * c1 * s1;
            float c3a = c2a * c1 - s2a * s1, s3a = s2a * c1 + c2a * s1;
            float t1 = h1x * c1  - h1y * s1;
            float t2 = h2x * c2a - h2y * s2a;
            float t3 = h3x * c3a - h3y * s3a;
            r0[j] = (h0x + t1 + t2 + t3) * inv;
            r1[j] = (h0x - t1 + t2 - t3) * inv;
            float u1 = g1x * c1  - g1y * s1;
            float u2 = g2x * c2a - g2y * s2a;
            float u3 = g3x * c3a - g3y * s3a;
            q0[j] = (g0x + u1 + u2 + u3) * inv;
            q1[j] = (g0x - u1 + u2 - u3) * inv;
            float nc = c1 * cr - s1 * sr;
            float ns = s1 * cr + c1 * sr;
            c1 = nc; s1 = ns;
        }
        __builtin_nontemporal_store(r0, (vfloat4*)(orow0 + lane * 4));
        __builtin_nontemporal_store(r1, (vfloat4*)(orow0 + 256 + lane * 4));
        __builtin_nontemporal_store(q0, (vfloat4*)(orow1 + lane * 4));
        __builtin_nontemporal_store(q1, (vfloat4*)(orow1 + 256 + lane * 4));
    }
}

extern "C" void kernel_launch(void* const* d_in, const int* in_sizes, int n_in,
                              void* d_out, int out_size, void* d_ws, size_t ws_size,
                              hipStream_t stream) {
    const float* x  = (const float*)d_in[0];
    const float* w1 = (const float*)d_in[3];
    const float* w2 = (const float*)d_in[4];
    float* out = (float*)d_out;

    float* Yg = (float*)d_ws;               // [8][16][8][64] floats = 256 KB

    k_dft_t<<<1024, 256, 0, stream>>>(x, Yg);
    k_mix_eval<<<2048, 256, 0, stream>>>(Yg, w1, w2, out);
}